// Round 9
// baseline (164.095 us; speedup 1.0000x reference)
//
#include <hip/hip_runtime.h>
#include <math.h>

#define HW    9216
#define KJ    17
#define BATCH 128
#define TOPK  8
#define NROW  (BATCH * KJ)   // 2176

typedef float f32x4 __attribute__((ext_vector_type(4)));  // clang vector:
// __builtin_nontemporal_load rejects HIP_vector_type (class) pointers.

// R9: nt loads (R8's win: fills no longer contend -> k1 60->~46us, total
// 163.5) + the 4-deep rotating prefetch ring (R3 structure). Rationale: R8
// moved the bottleneck — k1 now streams 3.4 TB/s vs 6.6 demonstrated by the
// fill kernel; nt makes every read a full-latency HBM round trip, and R8's
// one-volley-of-6 structure leaves each wave issue-idle in the latency
// shadow. The ring sustains 8 outstanding loads continuously per wave.
// All old ILP nulls (R0-R6) were measured under the fill-contention regime
// and are void. One variable vs R8: depth/structure.
__global__ __launch_bounds__(256, 6) void per_joint_mse(
    const float* __restrict__ outp, const float* __restrict__ tgt,
    const float* __restrict__ tw, float* __restrict__ pj)
{
    const int row = blockIdx.x;            // b*KJ + k
    const f32x4* o4 = (const f32x4*)(outp + (size_t)row * HW);
    const f32x4* t4 = (const f32x4*)(tgt  + (size_t)row * HW);
    const int tid = threadIdx.x;

    // Prologue: fill the 4-deep rotating buffer (8 nt loads in flight).
    f32x4 ob[4], tb[4];
#pragma unroll
    for (int j = 0; j < 4; ++j) {
        ob[j] = __builtin_nontemporal_load(o4 + tid + j * 256);
        tb[j] = __builtin_nontemporal_load(t4 + tid + j * 256);
    }

    float acc = 0.f;
    // Steady state: consume slot (j&3), immediately refill with load j+4.
    // Fully unrolled -> all ring indices compile-time constant (no scratch).
#pragma unroll
    for (int j = 0; j < 9; ++j) {
        const f32x4 o = ob[j & 3];
        const f32x4 t = tb[j & 3];
        if (j + 4 < 9) {
            ob[j & 3] = __builtin_nontemporal_load(o4 + tid + (j + 4) * 256);
            tb[j & 3] = __builtin_nontemporal_load(t4 + tid + (j + 4) * 256);
        }
        float d;
        d = o.x - t.x; acc = fmaf(d, d, acc);
        d = o.y - t.y; acc = fmaf(d, d, acc);
        d = o.z - t.z; acc = fmaf(d, d, acc);
        d = o.w - t.w; acc = fmaf(d, d, acc);
    }

    // wave64 shuffle reduce
#pragma unroll
    for (int off = 32; off > 0; off >>= 1)
        acc += __shfl_down(acc, off, 64);

    __shared__ float smem[4];
    if ((tid & 63) == 0) smem[tid >> 6] = acc;
    __syncthreads();
    if (tid == 0) {
        const float w = tw[row];
        const float tot = smem[0] + smem[1] + smem[2] + smem[3];
        pj[row] = tot * w * w * (1.0f / (float)HW);
    }
}

// Kernel 2: per-sample top-8-of-17, then mean over batch. 1 block, 128
// threads. Measured-free vs the ~96us of in-window harness re-poison fills
// (R4/R8 decode: fills write 320.8MB = the two input tensors each iter).
__global__ __launch_bounds__(128) void ohkm_reduce(
    const float* __restrict__ pj, float* __restrict__ result)
{
    const int b = threadIdx.x;   // 0..127 — one sample per thread
    float v[KJ];
#pragma unroll
    for (int k = 0; k < KJ; ++k) v[k] = pj[b * KJ + k];

    float s = 0.f;
#pragma unroll
    for (int t = 0; t < TOPK; ++t) {
        float m = v[0];
#pragma unroll
        for (int k = 1; k < KJ; ++k) m = fmaxf(m, v[k]);
        s += m;
        // remove exactly the FIRST element equal to m (tie-safe top_k semantics)
        bool removed = false;
#pragma unroll
        for (int k = 0; k < KJ; ++k) {
            const bool hit = (!removed) && (v[k] == m);
            v[k] = hit ? -INFINITY : v[k];
            removed = removed || hit;
        }
    }

    // 128 threads = 2 waves
#pragma unroll
    for (int off = 32; off > 0; off >>= 1)
        s += __shfl_down(s, off, 64);

    __shared__ float smem[2];
    if ((b & 63) == 0) smem[b >> 6] = s;
    __syncthreads();
    if (b == 0)
        result[0] = (smem[0] + smem[1]) * (1.0f / (float)(BATCH * TOPK));
}

extern "C" void kernel_launch(void* const* d_in, const int* in_sizes, int n_in,
                              void* d_out, int out_size, void* d_ws, size_t ws_size,
                              hipStream_t stream) {
    const float* outp = (const float*)d_in[0];   // [128,17,96,96]
    const float* tgt  = (const float*)d_in[1];   // [128,17,96,96]
    const float* tw   = (const float*)d_in[2];   // [128,17,1]
    float* result = (float*)d_out;               // scalar
    float* pj = (float*)d_ws;                    // [2176] per-joint MSE

    per_joint_mse<<<NROW, 256, 0, stream>>>(outp, tgt, tw, pj);
    ohkm_reduce<<<1, 128, 0, stream>>>(pj, result);
}